// Round 10
// baseline (38.325 us; speedup 1.0000x reference)
//
#include <hip/hip_runtime.h>
#include <hip/hip_bf16.h>

constexpr int S  = 256;
constexpr int D  = 768;
constexpr int KQ = 8;          // K slices
constexpr int KS = D / KQ;     // 96
constexpr int GROWS = KQ * S;  // 2048 floats: G[((batch*256+row)*8+kq)*256+col]

typedef _Float16 half8  __attribute__((ext_vector_type(8)));
typedef _Float16 half4v __attribute__((ext_vector_type(4)));
typedef float    f32x4  __attribute__((ext_vector_type(4)));

// Lower-triangle 64x64 tile positions (ti >= tj) of the 4x4 tile grid.
__device__ const int TI_MAP[10] = {0,1,1,2,2,2,3,3,3,3};
__device__ const int TJ_MAP[10] = {0,0,1,0,1,2,0,1,2,3};

// Split X into fp16 hi/lo: x = hi + lo + O(2^-22 x). Done ONCE (round-9
// post-mortem: fusing this into gram multiplied the work 8x). Also zeroes
// cnt[] for visxw's last-block-finalize protocol.
__global__ __launch_bounds__(256) void convert_kernel(const float* __restrict__ X,
                                                      _Float16* __restrict__ Xh,
                                                      _Float16* __restrict__ Xl,
                                                      unsigned* __restrict__ cnt) {
    if (blockIdx.x == 0 && threadIdx.x < 8) cnt[threadIdx.x] = 0u;
    const int i = (blockIdx.x * 256 + threadIdx.x) * 4;
    const float4 v = *(const float4*)(X + i);
    half4v h, l;
    h.x = (_Float16)v.x; l.x = (_Float16)(v.x - (float)h.x);
    h.y = (_Float16)v.y; l.y = (_Float16)(v.y - (float)h.y);
    h.z = (_Float16)v.z; l.z = (_Float16)(v.z - (float)h.z);
    h.w = (_Float16)v.w; l.w = (_Float16)(v.w - (float)h.w);
    *(half4v*)(Xh + i) = h;
    *(half4v*)(Xl + i) = l;
}

// Gram via MFMA, TRIANGLE TILES ONLY (stage 2 reads G[b][c] only for c <= b).
// G_slice = Ah*Bh^T + Ah*Bl^T + Al*Bh^T (fp32 accumulate); round-8-validated
// inner loop, bit-identical values. Grid (10, 8, 8) = 640 blocks (2.5/CU).
// K=96 staged once in LDS (53 KB); wave w owns rows 16w..+15 of its tile.
__global__ __launch_bounds__(256) void gram_kernel(const _Float16* __restrict__ Xh,
                                                   const _Float16* __restrict__ Xl,
                                                   float* __restrict__ G) {
    const int ti    = TI_MAP[blockIdx.x];
    const int tj    = TJ_MAP[blockIdx.x];
    const int batch = blockIdx.y;
    const int kq    = blockIdx.z;

    const size_t xoff = (size_t)batch * S * D + kq * KS;
    const _Float16* Xhq = Xh + xoff;
    const _Float16* Xlq = Xl + xoff;

    // stride 104 halfs = 208B: 16B-aligned; 4 x 13.3 KB = 53 KB
    __shared__ _Float16 Ah[64][104], Al[64][104], Bh[64][104], Bl[64][104];

    const int t    = threadIdx.x;
    const int srow = t >> 2;          // 0..63
    const int sk   = (t & 3) * 24;    // 0,24,48,72 (3 x 8-half chunks each)

#pragma unroll
    for (int c = 0; c < 3; ++c) {
        const int ko = sk + c * 8;    // 16B-aligned half offset
        *(int4*)&Ah[srow][ko] = *(const int4*)(Xhq + (size_t)(ti * 64 + srow) * D + ko);
        *(int4*)&Al[srow][ko] = *(const int4*)(Xlq + (size_t)(ti * 64 + srow) * D + ko);
        *(int4*)&Bh[srow][ko] = *(const int4*)(Xhq + (size_t)(tj * 64 + srow) * D + ko);
        *(int4*)&Bl[srow][ko] = *(const int4*)(Xlq + (size_t)(tj * 64 + srow) * D + ko);
    }
    __syncthreads();

    const int lane = t & 63;
    const int w    = t >> 6;          // wave -> rows 16w..16w+15
    const int frow = lane & 15;       // fragment row/col within 16
    const int fko  = (lane >> 4) * 8; // fragment k offset (8 halfs)

    f32x4 acc[4] = {};
#pragma unroll
    for (int ks = 0; ks < 3; ++ks) {
        const int k0 = ks * 32 + fko;
        const half8 ah = *(const half8*)&Ah[w * 16 + frow][k0];
        const half8 al = *(const half8*)&Al[w * 16 + frow][k0];
#pragma unroll
        for (int n = 0; n < 4; ++n) {
            const half8 bh = *(const half8*)&Bh[n * 16 + frow][k0];
            const half8 bl = *(const half8*)&Bl[n * 16 + frow][k0];
            acc[n] = __builtin_amdgcn_mfma_f32_16x16x32_f16(ah, bh, acc[n], 0, 0, 0);
            acc[n] = __builtin_amdgcn_mfma_f32_16x16x32_f16(ah, bl, acc[n], 0, 0, 0);
            acc[n] = __builtin_amdgcn_mfma_f32_16x16x32_f16(al, bh, acc[n], 0, 0, 0);
        }
    }

    // C/D layout (m89-verified): col = lane&15, row = (lane>>4)*4 + reg.
    float* gout = G + ((size_t)(batch * S + ti * 64 + w * 16 + (lane >> 4) * 4) * KQ + kq) * S
                    + tj * 64 + frow;
#pragma unroll
    for (int n = 0; n < 4; ++n)
#pragma unroll
        for (int r = 0; r < 4; ++r)
            gout[(size_t)r * GROWS + n * 16] = acc[n][r];
}

// Stage 2 (fused vis + P + head): wave handles b = blockIdx.x*4 + wave.
//   vis: contiguous 8-slice row read (8 KB) + triangle guard (4*lane <= b,
//        all read values lie in computed triangle tiles).
//   P:   p_k = x_b . W[:,k] -> P[b][:], wv[b].
//   Last block per batch (threadfence + counter, 64 bumps/batch) computes
//   logits = sum_s w_s P[s][:] and log_softmax -> d_out (r9-validated).
__global__ __launch_bounds__(256) void visxw_kernel(const float* __restrict__ X,
                                                    const float* __restrict__ Wm,
                                                    const float* __restrict__ G,
                                                    float* __restrict__ P,
                                                    float* __restrict__ wv,
                                                    unsigned* __restrict__ cnt,
                                                    float* __restrict__ out) {
    const int batch = blockIdx.y;
    const int wave  = threadIdx.x >> 6;
    const int lane  = threadIdx.x & 63;
    const int b     = blockIdx.x * 4 + wave;

    // ---- visibility of b from 0: sum 8 slice segments of row b ----
    const float* rbp = G + (size_t)(batch * S + b) * GROWS + 4 * lane;
    float4 s0 = make_float4(0.f, 0.f, 0.f, 0.f), s1 = s0, s2 = s0, s3 = s0;
    if (4 * lane <= b) {            // triangle: lanes past b contribute nothing
#pragma unroll
        for (int sl = 0; sl < 2; ++sl) {
            const float4 v0 = *(const float4*)(rbp + (size_t)(4 * sl + 0) * S);
            const float4 v1 = *(const float4*)(rbp + (size_t)(4 * sl + 1) * S);
            const float4 v2 = *(const float4*)(rbp + (size_t)(4 * sl + 2) * S);
            const float4 v3 = *(const float4*)(rbp + (size_t)(4 * sl + 3) * S);
            s0.x += v0.x; s0.y += v0.y; s0.z += v0.z; s0.w += v0.w;
            s1.x += v1.x; s1.y += v1.y; s1.z += v1.z; s1.w += v1.w;
            s2.x += v2.x; s2.y += v2.y; s2.z += v2.z; s2.w += v2.w;
            s3.x += v3.x; s3.y += v3.y; s3.z += v3.z; s3.w += v3.w;
        }
    }
    float4 gs;
    gs.x = (s0.x + s1.x) + (s2.x + s3.x);
    gs.y = (s0.y + s1.y) + (s2.y + s3.y);
    gs.z = (s0.z + s1.z) + (s2.z + s3.z);
    gs.w = (s0.w + s1.w) + (s2.w + s3.w);

    const int bq = b & 3;                       // wave-uniform component select
    float sel = (bq == 0) ? gs.x : ((bq == 1) ? gs.y : ((bq == 2) ? gs.z : gs.w));
    const float gb = __shfl(sel, b >> 2);
    const float g0 = __shfl(gs.x, 0);
    const float denom = (b > 0) ? (float)b : 1.0f;

    bool blocked = false;
    {
        const int c0 = 4 * lane;
#define VTEST(Q, GV) { const int c = c0 + (Q); \
        const float line = gb + ((g0 - gb) * (float)(b - c)) / denom; \
        if (c >= 1 && c < b && (GV) >= line) blocked = true; }
        VTEST(0, gs.x) VTEST(1, gs.y) VTEST(2, gs.z) VTEST(3, gs.w)
#undef VTEST
    }
    const bool visflag = (b >= 1) && !__any(blocked);

    // ---- P[b][:] = x_b @ W ----
    const float* xs = X + ((size_t)batch * S + b) * D;
    float a0 = 0.f, a1 = 0.f, a2 = 0.f, a3 = 0.f;
#pragma unroll
    for (int i = 0; i < 3; ++i) {
        const int d0 = (lane + 64 * i) * 4;
        const float4 xv = *(const float4*)(xs + d0);
        const float xf[4] = {xv.x, xv.y, xv.z, xv.w};
#pragma unroll
        for (int j = 0; j < 4; ++j) {
            const float4 wq = *(const float4*)(Wm + (size_t)(d0 + j) * 4);
            a0 = fmaf(xf[j], wq.x, a0);
            a1 = fmaf(xf[j], wq.y, a1);
            a2 = fmaf(xf[j], wq.z, a2);
            a3 = fmaf(xf[j], wq.w, a3);
        }
    }
#pragma unroll
    for (int off = 32; off; off >>= 1) {
        a0 += __shfl_xor(a0, off);
        a1 += __shfl_xor(a1, off);
        a2 += __shfl_xor(a2, off);
        a3 += __shfl_xor(a3, off);
    }
    if (lane == 0) {
        float4 o = {a0, a1, a2, a3};
        *(float4*)(P + ((size_t)batch * S + b) * 4) = o;
        wv[batch * S + b] = visflag ? 1.0f : 0.0f;
    }

    // ---- last block per batch finalizes the head ----
    __shared__ unsigned lastflag;
    __syncthreads();                 // all 4 waves' P/wv stores issued
    if (threadIdx.x == 0) {
        __threadfence();             // release: P/wv visible device-wide
        const unsigned old = atomicAdd(&cnt[batch], 1u);
        lastflag = (old == 63u) ? 1u : 0u;
    }
    __syncthreads();

    if (lastflag) {
        __threadfence();             // acquire side
        const int k = threadIdx.x >> 6;   // wave k -> logit k
        float sum = 0.f;
#pragma unroll
        for (int i = 0; i < 4; ++i) {
            const int s = lane + 64 * i;
            sum = fmaf(wv[batch * S + s], P[((size_t)batch * S + s) * 4 + k], sum);
        }
#pragma unroll
        for (int off = 32; off; off >>= 1) sum += __shfl_xor(sum, off);

        __shared__ float lsh[4];
        if (lane == 0) lsh[k] = sum;
        __syncthreads();

        if (threadIdx.x == 0) {
            const float l0 = lsh[0], l1 = lsh[1], l2 = lsh[2], l3 = lsh[3];
            const float m = fmaxf(fmaxf(l0, l1), fmaxf(l2, l3));
            const float lse = logf(expf(l0 - m) + expf(l1 - m) +
                                   expf(l2 - m) + expf(l3 - m));
            out[batch * 4 + 0] = l0 - m - lse;
            out[batch * 4 + 1] = l1 - m - lse;
            out[batch * 4 + 2] = l2 - m - lse;
            out[batch * 4 + 3] = l3 - m - lse;
        }
    }
}

extern "C" void kernel_launch(void* const* d_in, const int* in_sizes, int n_in,
                              void* d_out, int out_size, void* d_ws, size_t ws_size,
                              hipStream_t stream) {
    const float* X  = (const float*)d_in[0];   // [8, 256, 768] fp32
    const float* Wm = (const float*)d_in[1];   // [768, 4] fp32
    float* out = (float*)d_out;                // [8, 4] fp32

    float* ws = (float*)d_ws;
    float*    P   = ws;                              // 8192 floats
    float*    wv  = ws + 8192;                       // 2048 floats
    unsigned* cnt = (unsigned*)(ws + 10240);         // 8 uints
    float*    G   = ws + 10304;                      // 8*256*8*256 = 4.19M floats
    _Float16* Xh  = (_Float16*)(ws + 10304 + 4194304);
    _Float16* Xl  = Xh + (size_t)8 * S * D;          // 1.57M halfs each

    convert_kernel<<<1536,           256, 0, stream>>>(X, Xh, Xl, cnt);
    gram_kernel   <<<dim3(10, 8, 8), 256, 0, stream>>>(Xh, Xl, G);
    visxw_kernel  <<<dim3(64, 8),    256, 0, stream>>>(X, Wm, G, P, wv, cnt, out);
}

// Round 11
// 26.555 us; speedup vs baseline: 1.4433x; 1.4433x over previous
//
#include <hip/hip_runtime.h>
#include <hip/hip_bf16.h>

constexpr int S  = 256;
constexpr int D  = 768;
constexpr int KQ = 8;          // K slices
constexpr int KS = D / KQ;     // 96
constexpr int GROWS = KQ * S;  // 2048 floats: G[((batch*256+row)*8+kq)*256+col]

typedef _Float16 half8  __attribute__((ext_vector_type(8)));
typedef _Float16 half4v __attribute__((ext_vector_type(4)));
typedef float    f32x4  __attribute__((ext_vector_type(4)));

// Lower-triangle 64x64 tile positions (ti >= tj) of the 4x4 tile grid.
__device__ const int TI_MAP[10] = {0,1,1,2,2,2,3,3,3,3};
__device__ const int TJ_MAP[10] = {0,0,1,0,1,2,0,1,2,3};

// Fused convert + XW: one wave per row b.
//   - splits x_b into fp16 (hi, lo), written once (1x conversion count)
//   - P[b][:] = x_b @ W with the exact r8 fmaf order (bit-identical P)
// Grid (64, 8), 256 threads.
__global__ __launch_bounds__(256) void convxw_kernel(const float* __restrict__ X,
                                                     const float* __restrict__ Wm,
                                                     _Float16* __restrict__ Xh,
                                                     _Float16* __restrict__ Xl,
                                                     float* __restrict__ P) {
    const int batch = blockIdx.y;
    const int wave  = threadIdx.x >> 6;
    const int lane  = threadIdx.x & 63;
    const int b     = blockIdx.x * 4 + wave;

    const size_t rowoff = ((size_t)batch * S + b) * D;
    const float* xs = X + rowoff;

    float a0 = 0.f, a1 = 0.f, a2 = 0.f, a3 = 0.f;
#pragma unroll
    for (int i = 0; i < 3; ++i) {
        const int d0 = (lane + 64 * i) * 4;
        const float4 xv = *(const float4*)(xs + d0);

        half4v h, l;
        h.x = (_Float16)xv.x; l.x = (_Float16)(xv.x - (float)h.x);
        h.y = (_Float16)xv.y; l.y = (_Float16)(xv.y - (float)h.y);
        h.z = (_Float16)xv.z; l.z = (_Float16)(xv.z - (float)h.z);
        h.w = (_Float16)xv.w; l.w = (_Float16)(xv.w - (float)h.w);
        *(half4v*)(Xh + rowoff + d0) = h;
        *(half4v*)(Xl + rowoff + d0) = l;

        const float xf[4] = {xv.x, xv.y, xv.z, xv.w};
#pragma unroll
        for (int j = 0; j < 4; ++j) {
            const float4 wq = *(const float4*)(Wm + (size_t)(d0 + j) * 4);
            a0 = fmaf(xf[j], wq.x, a0);
            a1 = fmaf(xf[j], wq.y, a1);
            a2 = fmaf(xf[j], wq.z, a2);
            a3 = fmaf(xf[j], wq.w, a3);
        }
    }
#pragma unroll
    for (int off = 32; off; off >>= 1) {
        a0 += __shfl_xor(a0, off);
        a1 += __shfl_xor(a1, off);
        a2 += __shfl_xor(a2, off);
        a3 += __shfl_xor(a3, off);
    }
    if (lane == 0) {
        float4 o = {a0, a1, a2, a3};
        *(float4*)(P + ((size_t)batch * S + b) * 4) = o;
    }
}

// Gram via MFMA, TRIANGLE TILES ONLY (r10-validated, bit-exact values).
// G_slice = Ah*Bh^T + Ah*Bl^T + Al*Bh^T (fp32 accumulate).
// Grid (10, 8, 8) = 640 blocks; K=96 staged once in LDS (53 KB).
__global__ __launch_bounds__(256) void gram_kernel(const _Float16* __restrict__ Xh,
                                                   const _Float16* __restrict__ Xl,
                                                   float* __restrict__ G) {
    const int ti    = TI_MAP[blockIdx.x];
    const int tj    = TJ_MAP[blockIdx.x];
    const int batch = blockIdx.y;
    const int kq    = blockIdx.z;

    const size_t xoff = (size_t)batch * S * D + kq * KS;
    const _Float16* Xhq = Xh + xoff;
    const _Float16* Xlq = Xl + xoff;

    __shared__ _Float16 Ah[64][104], Al[64][104], Bh[64][104], Bl[64][104];

    const int t    = threadIdx.x;
    const int srow = t >> 2;          // 0..63
    const int sk   = (t & 3) * 24;    // 0,24,48,72

#pragma unroll
    for (int c = 0; c < 3; ++c) {
        const int ko = sk + c * 8;    // 16B-aligned half offset
        *(int4*)&Ah[srow][ko] = *(const int4*)(Xhq + (size_t)(ti * 64 + srow) * D + ko);
        *(int4*)&Al[srow][ko] = *(const int4*)(Xlq + (size_t)(ti * 64 + srow) * D + ko);
        *(int4*)&Bh[srow][ko] = *(const int4*)(Xhq + (size_t)(tj * 64 + srow) * D + ko);
        *(int4*)&Bl[srow][ko] = *(const int4*)(Xlq + (size_t)(tj * 64 + srow) * D + ko);
    }
    __syncthreads();

    const int lane = t & 63;
    const int w    = t >> 6;          // wave -> rows 16w..16w+15
    const int frow = lane & 15;
    const int fko  = (lane >> 4) * 8;

    f32x4 acc[4] = {};
#pragma unroll
    for (int ks = 0; ks < 3; ++ks) {
        const int k0 = ks * 32 + fko;
        const half8 ah = *(const half8*)&Ah[w * 16 + frow][k0];
        const half8 al = *(const half8*)&Al[w * 16 + frow][k0];
#pragma unroll
        for (int n = 0; n < 4; ++n) {
            const half8 bh = *(const half8*)&Bh[n * 16 + frow][k0];
            const half8 bl = *(const half8*)&Bl[n * 16 + frow][k0];
            acc[n] = __builtin_amdgcn_mfma_f32_16x16x32_f16(ah, bh, acc[n], 0, 0, 0);
            acc[n] = __builtin_amdgcn_mfma_f32_16x16x32_f16(ah, bl, acc[n], 0, 0, 0);
            acc[n] = __builtin_amdgcn_mfma_f32_16x16x32_f16(al, bh, acc[n], 0, 0, 0);
        }
    }

    // C/D layout (m89-verified): col = lane&15, row = (lane>>4)*4 + reg.
    float* gout = G + ((size_t)(batch * S + ti * 64 + w * 16 + (lane >> 4) * 4) * KQ + kq) * S
                    + tj * 64 + frow;
#pragma unroll
    for (int n = 0; n < 4; ++n)
#pragma unroll
        for (int r = 0; r < 4; ++r)
            gout[(size_t)r * GROWS + n * 16] = acc[n][r];
}

// Vis only: wave handles b = blockIdx.x*4 + wave; contiguous 8-slice row read
// (triangle-guarded), r8-validated test; writes wv[b]. No fences, no atomics.
__global__ __launch_bounds__(256) void vis_kernel(const float* __restrict__ G,
                                                  float* __restrict__ wv) {
    const int batch = blockIdx.y;
    const int wave  = threadIdx.x >> 6;
    const int lane  = threadIdx.x & 63;
    const int b     = blockIdx.x * 4 + wave;

    const float* rbp = G + (size_t)(batch * S + b) * GROWS + 4 * lane;
    float4 s0 = make_float4(0.f, 0.f, 0.f, 0.f), s1 = s0, s2 = s0, s3 = s0;
    if (4 * lane <= b) {            // triangle: lanes past b contribute nothing
#pragma unroll
        for (int sl = 0; sl < 2; ++sl) {
            const float4 v0 = *(const float4*)(rbp + (size_t)(4 * sl + 0) * S);
            const float4 v1 = *(const float4*)(rbp + (size_t)(4 * sl + 1) * S);
            const float4 v2 = *(const float4*)(rbp + (size_t)(4 * sl + 2) * S);
            const float4 v3 = *(const float4*)(rbp + (size_t)(4 * sl + 3) * S);
            s0.x += v0.x; s0.y += v0.y; s0.z += v0.z; s0.w += v0.w;
            s1.x += v1.x; s1.y += v1.y; s1.z += v1.z; s1.w += v1.w;
            s2.x += v2.x; s2.y += v2.y; s2.z += v2.z; s2.w += v2.w;
            s3.x += v3.x; s3.y += v3.y; s3.z += v3.z; s3.w += v3.w;
        }
    }
    float4 gs;
    gs.x = (s0.x + s1.x) + (s2.x + s3.x);
    gs.y = (s0.y + s1.y) + (s2.y + s3.y);
    gs.z = (s0.z + s1.z) + (s2.z + s3.z);
    gs.w = (s0.w + s1.w) + (s2.w + s3.w);

    const int bq = b & 3;                       // wave-uniform component select
    float sel = (bq == 0) ? gs.x : ((bq == 1) ? gs.y : ((bq == 2) ? gs.z : gs.w));
    const float gb = __shfl(sel, b >> 2);
    const float g0 = __shfl(gs.x, 0);
    const float denom = (b > 0) ? (float)b : 1.0f;

    bool blocked = false;
    {
        const int c0 = 4 * lane;
#define VTEST(Q, GV) { const int c = c0 + (Q); \
        const float line = gb + ((g0 - gb) * (float)(b - c)) / denom; \
        if (c >= 1 && c < b && (GV) >= line) blocked = true; }
        VTEST(0, gs.x) VTEST(1, gs.y) VTEST(2, gs.z) VTEST(3, gs.w)
#undef VTEST
    }
    const bool visflag = (b >= 1) && !__any(blocked);

    if (lane == 0) wv[batch * S + b] = visflag ? 1.0f : 0.0f;
}

// logits_k = sum_s w_s * P[s][k]; log_softmax. Grid 8 blocks, wave k per logit.
__global__ __launch_bounds__(256) void head_kernel(const float* __restrict__ P,
                                                   const float* __restrict__ wv,
                                                   float* __restrict__ out) {
    const int batch = blockIdx.x;
    const int k     = threadIdx.x >> 6;
    const int lane  = threadIdx.x & 63;

    float sum = 0.f;
#pragma unroll
    for (int i = 0; i < 4; ++i) {
        const int s = lane + 64 * i;
        sum = fmaf(wv[batch * S + s], P[((size_t)batch * S + s) * 4 + k], sum);
    }
#pragma unroll
    for (int off = 32; off; off >>= 1) sum += __shfl_xor(sum, off);

    __shared__ float lsh[4];
    if (lane == 0) lsh[k] = sum;
    __syncthreads();

    if (threadIdx.x == 0) {
        const float l0 = lsh[0], l1 = lsh[1], l2 = lsh[2], l3 = lsh[3];
        const float m = fmaxf(fmaxf(l0, l1), fmaxf(l2, l3));
        const float lse = logf(expf(l0 - m) + expf(l1 - m) + expf(l2 - m) + expf(l3 - m));
        out[batch * 4 + 0] = l0 - m - lse;
        out[batch * 4 + 1] = l1 - m - lse;
        out[batch * 4 + 2] = l2 - m - lse;
        out[batch * 4 + 3] = l3 - m - lse;
    }
}

extern "C" void kernel_launch(void* const* d_in, const int* in_sizes, int n_in,
                              void* d_out, int out_size, void* d_ws, size_t ws_size,
                              hipStream_t stream) {
    const float* X  = (const float*)d_in[0];   // [8, 256, 768] fp32
    const float* Wm = (const float*)d_in[1];   // [768, 4] fp32
    float* out = (float*)d_out;                // [8, 4] fp32

    float* ws = (float*)d_ws;
    float*    P  = ws;                               // 8192 floats
    float*    wv = ws + 8192;                        // 2048 floats
    float*    G  = ws + 10240;                       // 8*256*8*256 = 4.19M floats
    _Float16* Xh = (_Float16*)(ws + 10240 + 4194304);
    _Float16* Xl = Xh + (size_t)8 * S * D;           // 1.57M halfs each

    convxw_kernel<<<dim3(64, 8),    256, 0, stream>>>(X, Wm, Xh, Xl, P);
    gram_kernel  <<<dim3(10, 8, 8), 256, 0, stream>>>(Xh, Xl, G);
    vis_kernel   <<<dim3(64, 8),    256, 0, stream>>>(G, wv);
    head_kernel  <<<8,              256, 0, stream>>>(P, wv, out);
}

// Round 12
// 20.488 us; speedup vs baseline: 1.8706x; 1.2961x over previous
//
#include <hip/hip_runtime.h>
#include <hip/hip_bf16.h>

constexpr int S  = 256;
constexpr int D  = 768;
constexpr int KQ = 8;          // K slices
constexpr int KS = D / KQ;     // 96
constexpr int GROWS = KQ * S;  // 2048 floats: G[((batch*256+row)*8+kq)*256+col]

typedef _Float16 half8  __attribute__((ext_vector_type(8)));
typedef _Float16 half4v __attribute__((ext_vector_type(4)));
typedef float    f32x4  __attribute__((ext_vector_type(4)));

// Lower-triangle 64x64 tile positions (ti >= tj) of the 4x4 tile grid.
__device__ const int TI_MAP[10] = {0,1,1,2,2,2,3,3,3,3};
__device__ const int TJ_MAP[10] = {0,0,1,0,1,2,0,1,2,3};

// Gram via MFMA, triangle tiles, with the fp16 hi/lo split FUSED into staging
// (no Xh/Xl materialization: r11 moved 50 MB for it; conversion redundancy here
// is only 1.25x on reads and ~300 VALU/thread).
// G_slice = Ah*Bh^T + Ah*Bl^T + Al*Bh^T, fp32 MFMA accumulate. Conversion and
// MFMA arithmetic bit-identical to r10/r11-validated path -> G bit-identical.
// Grid (10, 8, 8) = 640 blocks, 256 threads, 53 KB LDS.
__global__ __launch_bounds__(256) void gram_kernel(const float* __restrict__ X,
                                                   float* __restrict__ G) {
    const int ti    = TI_MAP[blockIdx.x];
    const int tj    = TJ_MAP[blockIdx.x];
    const int batch = blockIdx.y;
    const int kq    = blockIdx.z;

    const float* Xq = X + (size_t)batch * S * D + kq * KS;

    // stride 104 halfs = 208B; 4 x 13.3 KB = 53 KB
    __shared__ _Float16 Ah[64][104], Al[64][104], Bh[64][104], Bl[64][104];

    const int t    = threadIdx.x;
    const int srow = t >> 2;          // 0..63
    const int sk   = (t & 3) * 24;    // 0,24,48,72 (24 floats = 6 float4 each)

    const float* pa = Xq + (size_t)(ti * 64 + srow) * D + sk;
    const float* pb = Xq + (size_t)(tj * 64 + srow) * D + sk;

#pragma unroll
    for (int c = 0; c < 6; ++c) {
        const int ko = sk + c * 4;
        const float4 va = *(const float4*)(pa + c * 4);
        const float4 vb = *(const float4*)(pb + c * 4);
        half4v ha, la, hb, lb;
        ha.x = (_Float16)va.x; la.x = (_Float16)(va.x - (float)ha.x);
        ha.y = (_Float16)va.y; la.y = (_Float16)(va.y - (float)ha.y);
        ha.z = (_Float16)va.z; la.z = (_Float16)(va.z - (float)ha.z);
        ha.w = (_Float16)va.w; la.w = (_Float16)(va.w - (float)ha.w);
        hb.x = (_Float16)vb.x; lb.x = (_Float16)(vb.x - (float)hb.x);
        hb.y = (_Float16)vb.y; lb.y = (_Float16)(vb.y - (float)hb.y);
        hb.z = (_Float16)vb.z; lb.z = (_Float16)(vb.z - (float)hb.z);
        hb.w = (_Float16)vb.w; lb.w = (_Float16)(vb.w - (float)hb.w);
        *(half4v*)&Ah[srow][ko] = ha;
        *(half4v*)&Al[srow][ko] = la;
        *(half4v*)&Bh[srow][ko] = hb;
        *(half4v*)&Bl[srow][ko] = lb;
    }
    __syncthreads();

    const int lane = t & 63;
    const int w    = t >> 6;          // wave -> rows 16w..16w+15
    const int frow = lane & 15;
    const int fko  = (lane >> 4) * 8;

    f32x4 acc[4] = {};
#pragma unroll
    for (int ks = 0; ks < 3; ++ks) {
        const int k0 = ks * 32 + fko;
        const half8 ah = *(const half8*)&Ah[w * 16 + frow][k0];
        const half8 al = *(const half8*)&Al[w * 16 + frow][k0];
#pragma unroll
        for (int n = 0; n < 4; ++n) {
            const half8 bh = *(const half8*)&Bh[n * 16 + frow][k0];
            const half8 bl = *(const half8*)&Bl[n * 16 + frow][k0];
            acc[n] = __builtin_amdgcn_mfma_f32_16x16x32_f16(ah, bh, acc[n], 0, 0, 0);
            acc[n] = __builtin_amdgcn_mfma_f32_16x16x32_f16(ah, bl, acc[n], 0, 0, 0);
            acc[n] = __builtin_amdgcn_mfma_f32_16x16x32_f16(al, bh, acc[n], 0, 0, 0);
        }
    }

    // C/D layout (m89-verified): col = lane&15, row = (lane>>4)*4 + reg.
    float* gout = G + ((size_t)(batch * S + ti * 64 + w * 16 + (lane >> 4) * 4) * KQ + kq) * S
                    + tj * 64 + frow;
#pragma unroll
    for (int n = 0; n < 4; ++n)
#pragma unroll
        for (int r = 0; r < 4; ++r)
            gout[(size_t)r * GROWS + n * 16] = acc[n][r];
}

// Stage 2 (r5-validated fusion): wave handles b = blockIdx.x*4 + wave.
//   vis: contiguous 8-slice row read + triangle guard -> wv[b]
//   P:   P[b][:] = x_b @ W
// No fences, no atomics (r10/r11 post-mortem: device-scope finalize ~ +12 us).
__global__ __launch_bounds__(256) void visxw_kernel(const float* __restrict__ X,
                                                    const float* __restrict__ Wm,
                                                    const float* __restrict__ G,
                                                    float* __restrict__ P,
                                                    float* __restrict__ wv) {
    const int batch = blockIdx.y;
    const int wave  = threadIdx.x >> 6;
    const int lane  = threadIdx.x & 63;
    const int b     = blockIdx.x * 4 + wave;

    // ---- visibility of b from 0 ----
    const float* rbp = G + (size_t)(batch * S + b) * GROWS + 4 * lane;
    float4 s0 = make_float4(0.f, 0.f, 0.f, 0.f), s1 = s0, s2 = s0, s3 = s0;
    if (4 * lane <= b) {            // triangle: lanes past b contribute nothing
#pragma unroll
        for (int sl = 0; sl < 2; ++sl) {
            const float4 v0 = *(const float4*)(rbp + (size_t)(4 * sl + 0) * S);
            const float4 v1 = *(const float4*)(rbp + (size_t)(4 * sl + 1) * S);
            const float4 v2 = *(const float4*)(rbp + (size_t)(4 * sl + 2) * S);
            const float4 v3 = *(const float4*)(rbp + (size_t)(4 * sl + 3) * S);
            s0.x += v0.x; s0.y += v0.y; s0.z += v0.z; s0.w += v0.w;
            s1.x += v1.x; s1.y += v1.y; s1.z += v1.z; s1.w += v1.w;
            s2.x += v2.x; s2.y += v2.y; s2.z += v2.z; s2.w += v2.w;
            s3.x += v3.x; s3.y += v3.y; s3.z += v3.z; s3.w += v3.w;
        }
    }
    float4 gs;
    gs.x = (s0.x + s1.x) + (s2.x + s3.x);
    gs.y = (s0.y + s1.y) + (s2.y + s3.y);
    gs.z = (s0.z + s1.z) + (s2.z + s3.z);
    gs.w = (s0.w + s1.w) + (s2.w + s3.w);

    const int bq = b & 3;                       // wave-uniform component select
    float sel = (bq == 0) ? gs.x : ((bq == 1) ? gs.y : ((bq == 2) ? gs.z : gs.w));
    const float gb = __shfl(sel, b >> 2);
    const float g0 = __shfl(gs.x, 0);
    const float denom = (b > 0) ? (float)b : 1.0f;

    bool blocked = false;
    {
        const int c0 = 4 * lane;
#define VTEST(Q, GV) { const int c = c0 + (Q); \
        const float line = gb + ((g0 - gb) * (float)(b - c)) / denom; \
        if (c >= 1 && c < b && (GV) >= line) blocked = true; }
        VTEST(0, gs.x) VTEST(1, gs.y) VTEST(2, gs.z) VTEST(3, gs.w)
#undef VTEST
    }
    const bool visflag = (b >= 1) && !__any(blocked);

    // ---- P[b][:] = x_b @ W ----
    const float* xs = X + ((size_t)batch * S + b) * D;
    float a0 = 0.f, a1 = 0.f, a2 = 0.f, a3 = 0.f;
#pragma unroll
    for (int i = 0; i < 3; ++i) {
        const int d0 = (lane + 64 * i) * 4;
        const float4 xv = *(const float4*)(xs + d0);
        const float xf[4] = {xv.x, xv.y, xv.z, xv.w};
#pragma unroll
        for (int j = 0; j < 4; ++j) {
            const float4 wq = *(const float4*)(Wm + (size_t)(d0 + j) * 4);
            a0 = fmaf(xf[j], wq.x, a0);
            a1 = fmaf(xf[j], wq.y, a1);
            a2 = fmaf(xf[j], wq.z, a2);
            a3 = fmaf(xf[j], wq.w, a3);
        }
    }
#pragma unroll
    for (int off = 32; off; off >>= 1) {
        a0 += __shfl_xor(a0, off);
        a1 += __shfl_xor(a1, off);
        a2 += __shfl_xor(a2, off);
        a3 += __shfl_xor(a3, off);
    }
    if (lane == 0) {
        float4 o = {a0, a1, a2, a3};
        *(float4*)(P + ((size_t)batch * S + b) * 4) = o;
        wv[batch * S + b] = visflag ? 1.0f : 0.0f;
    }
}

// logits_k = sum_s w_s * P[s][k]; log_softmax. Grid 8 blocks, wave k per logit.
__global__ __launch_bounds__(256) void head_kernel(const float* __restrict__ P,
                                                   const float* __restrict__ wv,
                                                   float* __restrict__ out) {
    const int batch = blockIdx.x;
    const int k     = threadIdx.x >> 6;
    const int lane  = threadIdx.x & 63;

    float sum = 0.f;
#pragma unroll
    for (int i = 0; i < 4; ++i) {
        const int s = lane + 64 * i;
        sum = fmaf(wv[batch * S + s], P[((size_t)batch * S + s) * 4 + k], sum);
    }
#pragma unroll
    for (int off = 32; off; off >>= 1) sum += __shfl_xor(sum, off);

    __shared__ float lsh[4];
    if (lane == 0) lsh[k] = sum;
    __syncthreads();

    if (threadIdx.x == 0) {
        const float l0 = lsh[0], l1 = lsh[1], l2 = lsh[2], l3 = lsh[3];
        const float m = fmaxf(fmaxf(l0, l1), fmaxf(l2, l3));
        const float lse = logf(expf(l0 - m) + expf(l1 - m) + expf(l2 - m) + expf(l3 - m));
        out[batch * 4 + 0] = l0 - m - lse;
        out[batch * 4 + 1] = l1 - m - lse;
        out[batch * 4 + 2] = l2 - m - lse;
        out[batch * 4 + 3] = l3 - m - lse;
    }
}

extern "C" void kernel_launch(void* const* d_in, const int* in_sizes, int n_in,
                              void* d_out, int out_size, void* d_ws, size_t ws_size,
                              hipStream_t stream) {
    const float* X  = (const float*)d_in[0];   // [8, 256, 768] fp32
    const float* Wm = (const float*)d_in[1];   // [768, 4] fp32
    float* out = (float*)d_out;                // [8, 4] fp32

    float* ws = (float*)d_ws;
    float* P  = ws;                            // 8192 floats
    float* wv = ws + 8192;                     // 2048 floats
    float* G  = ws + 10240;                    // 8*256*8*256 = 4.19M floats (16.8 MB)

    gram_kernel <<<dim3(10, 8, 8), 256, 0, stream>>>(X, G);
    visxw_kernel<<<dim3(64, 8),    256, 0, stream>>>(X, Wm, G, P, wv);
    head_kernel <<<8,              256, 0, stream>>>(P, wv, out);
}

// Round 13
// 19.693 us; speedup vs baseline: 1.9461x; 1.0404x over previous
//
#include <hip/hip_runtime.h>
#include <hip/hip_bf16.h>

constexpr int S  = 256;
constexpr int D  = 768;
constexpr int KQ = 8;          // K slices
constexpr int KS = D / KQ;     // 96
constexpr int GROWS = KQ * S;  // 2048 floats: G[((batch*256+row)*8+kq)*256+col]

typedef _Float16 half8  __attribute__((ext_vector_type(8)));
typedef _Float16 half4v __attribute__((ext_vector_type(4)));
typedef float    f32x4  __attribute__((ext_vector_type(4)));

// Lower-triangle 64x64 tile positions (ti >= tj) of the 4x4 tile grid.
__device__ const int TI_MAP[10] = {0,1,1,2,2,2,3,3,3,3};
__device__ const int TJ_MAP[10] = {0,0,1,0,1,2,0,1,2,3};

// Gram via MFMA, triangle tiles, fused fp16 hi/lo split (r12-validated).
// New in r13:
//  - diagonal blocks (ti==tj) alias B->A: skip the duplicate panel staging.
//  - diagonal blocks compute Ppart[row][kq][0..3] = sum_{k in slice} x[k]*W[k][:]
//    from the fp32 staging registers (X@W fused; visxw no longer reads X).
// G values bit-identical to r12. Grid (10, 8, 8) = 640 blocks, 256 threads.
__global__ __launch_bounds__(256) void gram_kernel(const float* __restrict__ X,
                                                   const float* __restrict__ Wm,
                                                   float* __restrict__ G,
                                                   float* __restrict__ Ppart) {
    const int ti    = TI_MAP[blockIdx.x];
    const int tj    = TJ_MAP[blockIdx.x];
    const int batch = blockIdx.y;
    const int kq    = blockIdx.z;
    const bool diag = (ti == tj);

    const float* Xq = X + (size_t)batch * S * D + kq * KS;

    __shared__ _Float16 AhS[64][104], AlS[64][104], BhS[64][104], BlS[64][104];
    __shared__ float Ws[96][4];    // W slice for the fused X@W partial

    const int t    = threadIdx.x;
    const int srow = t >> 2;          // 0..63 (shared by 4 consecutive lanes)
    const int sk   = (t & 3) * 24;    // k-quarter within the 96-wide slice

    if (diag && t < 96)
        *(float4*)&Ws[t][0] = *(const float4*)(Wm + (size_t)(kq * KS + t) * 4);

    const float* pa = Xq + (size_t)(ti * 64 + srow) * D + sk;
    const float* pb = Xq + (size_t)(tj * 64 + srow) * D + sk;

    float4 xva[6];                    // fp32 stash for the fused P partial
#pragma unroll
    for (int c = 0; c < 6; ++c) {
        const int ko = sk + c * 4;
        const float4 va = *(const float4*)(pa + c * 4);
        xva[c] = va;
        half4v ha, la;
        ha.x = (_Float16)va.x; la.x = (_Float16)(va.x - (float)ha.x);
        ha.y = (_Float16)va.y; la.y = (_Float16)(va.y - (float)ha.y);
        ha.z = (_Float16)va.z; la.z = (_Float16)(va.z - (float)ha.z);
        ha.w = (_Float16)va.w; la.w = (_Float16)(va.w - (float)ha.w);
        *(half4v*)&AhS[srow][ko] = ha;
        *(half4v*)&AlS[srow][ko] = la;
    }
    if (!diag) {
#pragma unroll
        for (int c = 0; c < 6; ++c) {
            const int ko = sk + c * 4;
            const float4 vb = *(const float4*)(pb + c * 4);
            half4v hb, lb;
            hb.x = (_Float16)vb.x; lb.x = (_Float16)(vb.x - (float)hb.x);
            hb.y = (_Float16)vb.y; lb.y = (_Float16)(vb.y - (float)hb.y);
            hb.z = (_Float16)vb.z; lb.z = (_Float16)(vb.z - (float)hb.z);
            hb.w = (_Float16)vb.w; lb.w = (_Float16)(vb.w - (float)hb.w);
            *(half4v*)&BhS[srow][ko] = hb;
            *(half4v*)&BlS[srow][ko] = lb;
        }
    }
    __syncthreads();

    // ---- fused X@W partial (diagonal blocks only) ----
    if (diag) {
        float4 pacc = make_float4(0.f, 0.f, 0.f, 0.f);
#pragma unroll
        for (int c = 0; c < 6; ++c) {
            const float xf[4] = {xva[c].x, xva[c].y, xva[c].z, xva[c].w};
#pragma unroll
            for (int q = 0; q < 4; ++q) {
                const float4 wq = *(const float4*)&Ws[sk + c * 4 + q][0];
                pacc.x = fmaf(xf[q], wq.x, pacc.x);
                pacc.y = fmaf(xf[q], wq.y, pacc.y);
                pacc.z = fmaf(xf[q], wq.z, pacc.z);
                pacc.w = fmaf(xf[q], wq.w, pacc.w);
            }
        }
#pragma unroll
        for (int off = 1; off <= 2; off <<= 1) {     // 4-lane group = one row
            pacc.x += __shfl_xor(pacc.x, off);
            pacc.y += __shfl_xor(pacc.y, off);
            pacc.z += __shfl_xor(pacc.z, off);
            pacc.w += __shfl_xor(pacc.w, off);
        }
        if ((t & 3) == 0)
            *(float4*)(Ppart + (((size_t)batch * S + ti * 64 + srow) * KQ + kq) * 4) = pacc;
    }

    // ---- MFMA (B aliased to A for diagonal tiles) ----
    _Float16 (*Bh)[104] = diag ? AhS : BhS;
    _Float16 (*Bl)[104] = diag ? AlS : BlS;

    const int lane = t & 63;
    const int w    = t >> 6;          // wave -> rows 16w..16w+15
    const int frow = lane & 15;
    const int fko  = (lane >> 4) * 8;

    f32x4 acc[4] = {};
#pragma unroll
    for (int ks = 0; ks < 3; ++ks) {
        const int k0 = ks * 32 + fko;
        const half8 ah = *(const half8*)&AhS[w * 16 + frow][k0];
        const half8 al = *(const half8*)&AlS[w * 16 + frow][k0];
#pragma unroll
        for (int n = 0; n < 4; ++n) {
            const half8 bh = *(const half8*)&Bh[n * 16 + frow][k0];
            const half8 bl = *(const half8*)&Bl[n * 16 + frow][k0];
            acc[n] = __builtin_amdgcn_mfma_f32_16x16x32_f16(ah, bh, acc[n], 0, 0, 0);
            acc[n] = __builtin_amdgcn_mfma_f32_16x16x32_f16(ah, bl, acc[n], 0, 0, 0);
            acc[n] = __builtin_amdgcn_mfma_f32_16x16x32_f16(al, bh, acc[n], 0, 0, 0);
        }
    }

    // C/D layout (m89-verified): col = lane&15, row = (lane>>4)*4 + reg.
    float* gout = G + ((size_t)(batch * S + ti * 64 + w * 16 + (lane >> 4) * 4) * KQ + kq) * S
                    + tj * 64 + frow;
#pragma unroll
    for (int n = 0; n < 4; ++n)
#pragma unroll
        for (int r = 0; r < 4; ++r)
            gout[(size_t)r * GROWS + n * 16] = acc[n][r];
}

// Vis only (r12-validated test, G reads only): wave handles b = blockIdx.x*4+wave.
__global__ __launch_bounds__(256) void vis_kernel(const float* __restrict__ G,
                                                  float* __restrict__ wv) {
    const int batch = blockIdx.y;
    const int wave  = threadIdx.x >> 6;
    const int lane  = threadIdx.x & 63;
    const int b     = blockIdx.x * 4 + wave;

    const float* rbp = G + (size_t)(batch * S + b) * GROWS + 4 * lane;
    float4 s0 = make_float4(0.f, 0.f, 0.f, 0.f), s1 = s0, s2 = s0, s3 = s0;
    if (4 * lane <= b) {            // triangle: lanes past b contribute nothing
#pragma unroll
        for (int sl = 0; sl < 2; ++sl) {
            const float4 v0 = *(const float4*)(rbp + (size_t)(4 * sl + 0) * S);
            const float4 v1 = *(const float4*)(rbp + (size_t)(4 * sl + 1) * S);
            const float4 v2 = *(const float4*)(rbp + (size_t)(4 * sl + 2) * S);
            const float4 v3 = *(const float4*)(rbp + (size_t)(4 * sl + 3) * S);
            s0.x += v0.x; s0.y += v0.y; s0.z += v0.z; s0.w += v0.w;
            s1.x += v1.x; s1.y += v1.y; s1.z += v1.z; s1.w += v1.w;
            s2.x += v2.x; s2.y += v2.y; s2.z += v2.z; s2.w += v2.w;
            s3.x += v3.x; s3.y += v3.y; s3.z += v3.z; s3.w += v3.w;
        }
    }
    float4 gs;
    gs.x = (s0.x + s1.x) + (s2.x + s3.x);
    gs.y = (s0.y + s1.y) + (s2.y + s3.y);
    gs.z = (s0.z + s1.z) + (s2.z + s3.z);
    gs.w = (s0.w + s1.w) + (s2.w + s3.w);

    const int bq = b & 3;                       // wave-uniform component select
    float sel = (bq == 0) ? gs.x : ((bq == 1) ? gs.y : ((bq == 2) ? gs.z : gs.w));
    const float gb = __shfl(sel, b >> 2);
    const float g0 = __shfl(gs.x, 0);
    const float denom = (b > 0) ? (float)b : 1.0f;

    bool blocked = false;
    {
        const int c0 = 4 * lane;
#define VTEST(Q, GV) { const int c = c0 + (Q); \
        const float line = gb + ((g0 - gb) * (float)(b - c)) / denom; \
        if (c >= 1 && c < b && (GV) >= line) blocked = true; }
        VTEST(0, gs.x) VTEST(1, gs.y) VTEST(2, gs.z) VTEST(3, gs.w)
#undef VTEST
    }
    const bool visflag = (b >= 1) && !__any(blocked);

    if (lane == 0) wv[batch * S + b] = visflag ? 1.0f : 0.0f;
}

// Head: logits_k = sum_s wv_s * sum_kq Ppart[s][kq][k]; log_softmax.
// Grid 8 blocks x 256 threads; thread t owns position s = t (128 B contiguous read).
__global__ __launch_bounds__(256) void head_kernel(const float* __restrict__ Ppart,
                                                   const float* __restrict__ wv,
                                                   float* __restrict__ out) {
    const int batch = blockIdx.x;
    const int t     = threadIdx.x;
    const int wave  = t >> 6;
    const int lane  = t & 63;

    float4 acc = make_float4(0.f, 0.f, 0.f, 0.f);
    if (wv[batch * S + t] != 0.0f) {
        const float* pp = Ppart + ((size_t)batch * S + t) * (KQ * 4);
#pragma unroll
        for (int kq = 0; kq < KQ; ++kq) {
            const float4 p = *(const float4*)(pp + kq * 4);
            acc.x += p.x; acc.y += p.y; acc.z += p.z; acc.w += p.w;
        }
    }
#pragma unroll
    for (int off = 32; off; off >>= 1) {
        acc.x += __shfl_xor(acc.x, off);
        acc.y += __shfl_xor(acc.y, off);
        acc.z += __shfl_xor(acc.z, off);
        acc.w += __shfl_xor(acc.w, off);
    }

    __shared__ float4 lsh[4];
    if (lane == 0) lsh[wave] = acc;
    __syncthreads();

    if (t == 0) {
        const float l0 = ((lsh[0].x + lsh[1].x) + (lsh[2].x + lsh[3].x));
        const float l1 = ((lsh[0].y + lsh[1].y) + (lsh[2].y + lsh[3].y));
        const float l2 = ((lsh[0].z + lsh[1].z) + (lsh[2].z + lsh[3].z));
        const float l3 = ((lsh[0].w + lsh[1].w) + (lsh[2].w + lsh[3].w));
        const float m = fmaxf(fmaxf(l0, l1), fmaxf(l2, l3));
        const float lse = logf(expf(l0 - m) + expf(l1 - m) + expf(l2 - m) + expf(l3 - m));
        out[batch * 4 + 0] = l0 - m - lse;
        out[batch * 4 + 1] = l1 - m - lse;
        out[batch * 4 + 2] = l2 - m - lse;
        out[batch * 4 + 3] = l3 - m - lse;
    }
}

extern "C" void kernel_launch(void* const* d_in, const int* in_sizes, int n_in,
                              void* d_out, int out_size, void* d_ws, size_t ws_size,
                              hipStream_t stream) {
    const float* X  = (const float*)d_in[0];   // [8, 256, 768] fp32
    const float* Wm = (const float*)d_in[1];   // [768, 4] fp32
    float* out = (float*)d_out;                // [8, 4] fp32

    float* ws = (float*)d_ws;
    float* Ppart = ws;                         // 8*256*8*4 = 65536 floats (256 KB)
    float* wv    = ws + 65536;                 // 2048 floats
    float* G     = ws + 65536 + 2048;          // 8*256*8*256 = 4.19M floats (16.8 MB)

    gram_kernel<<<dim3(10, 8, 8), 256, 0, stream>>>(X, Wm, G, Ppart);
    vis_kernel <<<dim3(64, 8),    256, 0, stream>>>(G, wv);
    head_kernel<<<8,              256, 0, stream>>>(Ppart, wv, out);
}